// Round 6
// baseline (363.497 us; speedup 1.0000x reference)
//
#include <hip/hip_runtime.h>
#include <hip/hip_fp16.h>

#define F_IN 61
#define H 32
#define BUCK_BITS 8                  // 256 nodes per bucket
#define BUCK_SZ   256
#define CHUNK     8192               // edges per block in hist/bin passes
#define XPAD 72                      // fp16 row pad: 144B rows -> 16B aligned b128 reads
#define CMAX 6144                    // binC LDS-staged bucket capacity (mean 4096, 32 sigma)

typedef _Float16 f16x8 __attribute__((ext_vector_type(8)));
typedef float    f32x4 __attribute__((ext_vector_type(4)));

// ---------- scan level 1: per-256-block exclusive scan + block totals ----------
__global__ __launch_bounds__(256) void scan1_kernel(const int* __restrict__ in,
                                                    int* __restrict__ scanned,
                                                    int* __restrict__ btot, int n) {
    __shared__ int s[256];
    int tid = threadIdx.x;
    int i = blockIdx.x * 256 + tid;
    int v = (i < n) ? in[i] : 0;
    s[tid] = v;
    __syncthreads();
    for (int off = 1; off < 256; off <<= 1) {
        int t = (tid >= off) ? s[tid - off] : 0;
        __syncthreads();
        s[tid] += t;
        __syncthreads();
    }
    if (i < n) scanned[i] = s[tid] - v;
    if (tid == 255) btot[blockIdx.x] = s[255];
}

// ---------- scan level 2: exclusive scan of block totals (single block) ----------
__global__ __launch_bounds__(1024) void scan2_kernel(int* __restrict__ btot, int nB) {
    __shared__ int s[1024];
    int tid = threadIdx.x;
    int v = (tid < nB) ? btot[tid] : 0;
    s[tid] = v;
    __syncthreads();
    for (int off = 1; off < 1024; off <<= 1) {
        int t = (tid >= off) ? s[tid - off] : 0;
        __syncthreads();
        s[tid] += t;
        __syncthreads();
    }
    if (tid < nB) btot[tid] = s[tid] - v;
}

// ---------- pass A: per-(block,bucket) histogram; block 0 also zeroes gs ----------
__global__ __launch_bounds__(256) void histA_kernel(const int* __restrict__ ei,
                                                    int* __restrict__ counts,
                                                    float* __restrict__ gs,
                                                    int E, int B, int nbuck) {
    __shared__ int h[640];
    int tid = threadIdx.x;
    if (blockIdx.x == 0) {
        #pragma unroll
        for (int r = 0; r < 8; r++) gs[r * 256 + tid] = 0.f;   // 64*H floats
    }
    for (int i = tid; i < nbuck; i += 256) h[i] = 0;
    __syncthreads();
    int e0 = blockIdx.x * CHUNK;
    int e1 = e0 + CHUNK; if (e1 > E) e1 = E;
    for (int e = e0 + tid; e < e1; e += 256)
        atomicAdd(&h[ei[E + e] >> BUCK_BITS], 1);
    __syncthreads();
    for (int i = tid; i < nbuck; i += 256) counts[i * B + blockIdx.x] = h[i];
}

// ---------- pass B: bin edges into per-(block,bucket) EXCLUSIVE ranges ----------
// Reads scan results directly (scan3 folded): excl[i] = countsS[i] + btot[i>>8].
// pack = (src<<8)|(dst&255); src < 2^18 fits.
__global__ __launch_bounds__(256) void binB_kernel(const int* __restrict__ ei,
                                                   const int* __restrict__ countsS,
                                                   const int* __restrict__ btot,
                                                   int* __restrict__ tmp,
                                                   int E, int B, int nbuck) {
    __shared__ int lcur[640];
    int tid = threadIdx.x;
    for (int i = tid; i < nbuck; i += 256) {
        int ci = i * B + blockIdx.x;
        lcur[i] = countsS[ci] + btot[ci >> 8];
    }
    __syncthreads();
    int e0 = blockIdx.x * CHUNK;
    int e1 = e0 + CHUNK; if (e1 > E) e1 = E;
    for (int e = e0 + tid; e < e1; e += 256) {
        int s = ei[e];
        int d = ei[E + e];
        int pos = atomicAdd(&lcur[d >> BUCK_BITS], 1);
        tmp[pos] = (s << BUCK_BITS) | (d & (BUCK_SZ - 1));
    }
}

// ---------- pass C: per-bucket degree + row_start + dinv + final CSR scatter ----------
// SINGLE global pass over tmp: the bucket slice (<= CMAX entries, uniform-branch
// fallback otherwise) is staged in LDS during the hist pass; the scatter then
// runs from LDS into an LDS obuf (local positions) and the final src_sorted
// write is a contiguous fully-coalesced copy. Removes the 2nd 9.6MB global
// read and the random 4B global scatter of the old 2-pass version.
// src_sorted stores BYTE offsets (src*64) for the fp16 row table.
// Block 0 also writes the zero rows (index N) of both fp16 buffers.
__global__ __launch_bounds__(256) void binC_kernel(const int* __restrict__ countsS,
                                                   const int* __restrict__ btot,
                                                   const int* __restrict__ tmp,
                                                   int* __restrict__ src_sorted,
                                                   int* __restrict__ row_start,
                                                   float* __restrict__ dinv,
                                                   __half* __restrict__ bufA,
                                                   __half* __restrict__ bufB,
                                                   int N, int E, int B, int nbuck) {
    __shared__ int hist[BUCK_SZ];
    __shared__ int pre[BUCK_SZ];
    __shared__ int lcur[BUCK_SZ];
    __shared__ int ebuf[CMAX];
    __shared__ int obuf[CMAX];
    int tid = threadIdx.x;
    int b = blockIdx.x;
    int base = b << BUCK_BITS;
    if (b == 0 && tid < H) {                 // zero rows for padded gathers
        bufA[(size_t)N * H + tid] = __float2half(0.f);
        bufB[(size_t)N * H + tid] = __float2half(0.f);
    }
    int c0 = b * B;
    int e0 = countsS[c0] + btot[c0 >> 8];
    int e1 = E;
    if (b + 1 < nbuck) {
        int c1 = (b + 1) * B;
        e1 = countsS[c1] + btot[c1 >> 8];
    }
    int cnt = e1 - e0;
    bool fits = (cnt <= CMAX);               // block-uniform
    hist[tid] = 0;
    __syncthreads();
    if (fits) {
        for (int j = tid; j < cnt; j += 256) {
            int p = tmp[e0 + j];
            ebuf[j] = p;
            atomicAdd(&hist[p & (BUCK_SZ - 1)], 1);
        }
    } else {
        for (int j = tid; j < cnt; j += 256)
            atomicAdd(&hist[tmp[e0 + j] & (BUCK_SZ - 1)], 1);
    }
    __syncthreads();
    int v = hist[tid];
    pre[tid] = v;
    __syncthreads();
    for (int off = 1; off < 256; off <<= 1) {
        int t = (tid >= off) ? pre[tid - off] : 0;
        __syncthreads();
        pre[tid] += t;
        __syncthreads();
    }
    int excl = pre[tid] - v;
    int node = base + tid;
    if (node < N) {
        row_start[node] = e0 + excl;
        dinv[node] = rsqrtf((float)v + 1.0f);     // +1 self-loop
        if (node == N - 1) row_start[N] = E;
    }
    lcur[tid] = fits ? excl : (e0 + excl);
    __syncthreads();
    if (fits) {
        for (int j = tid; j < cnt; j += 256) {
            int p = ebuf[j];
            int pos = atomicAdd(&lcur[p & (BUCK_SZ - 1)], 1);
            obuf[pos] = (p >> BUCK_BITS) << 6;    // byte offset of fp16 row
        }
        __syncthreads();
        for (int j = tid; j < cnt; j += 256)      // coalesced stream-out
            src_sorted[e0 + j] = obuf[j];
    } else {
        for (int j = tid; j < cnt; j += 256) {
            int p = tmp[e0 + j];
            int pos = atomicAdd(&lcur[p & (BUCK_SZ - 1)], 1);
            src_sorted[pos] = (p >> BUCK_BITS) << 6;
        }
    }
}

// ---------- layer 1 dense via MFMA: hs1 = fp16( dinv * (x @ W1) ) ----------
// 64 nodes/block, 4 waves, each wave one 16-node M-tile. x and W^T staged as
// fp16 in LDS with 72-element row pad (144B rows: 16B-aligned ds_read_b128,
// even bank spread). K padded 61->64 with zeros. Per wave: 4 MFMAs
// (2 f-tiles x 2 K-steps), fp32 accumulate, dinv scale in epilogue.
__global__ __launch_bounds__(256) void gemm1_kernel(const float* __restrict__ x,
                                                    const float* __restrict__ W,
                                                    const float* __restrict__ dinv,
                                                    __half* __restrict__ h, int N) {
    __shared__ _Float16 Wt[H * XPAD];      // Wt[f][k] = W[k*32+f], k<61 else 0
    __shared__ _Float16 xs[64 * XPAD];     // xs[n][k], k<61 else 0
    int tid = threadIdx.x;
    for (int i = tid; i < 2048; i += 256) {          // k = 0..63, f = 0..31
        int k = i >> 5, f = i & 31;
        Wt[f * XPAD + k] = (k < F_IN) ? (_Float16)W[k * H + f] : (_Float16)0.f;
    }
    int nb = blockIdx.x * 64;
    int navail = N - nb; if (navail > 64) navail = 64;
    int lim = navail * F_IN;
    const float* xb = x + (long long)nb * F_IN;
    for (int i = tid; i < 64 * F_IN; i += 256) {     // coalesced dword stream
        int n = i / F_IN, k = i - n * F_IN;
        xs[n * XPAD + k] = (i < lim) ? (_Float16)xb[i] : (_Float16)0.f;
    }
    if (tid < 192) {                                  // zero pad k = 61..63
        int n = tid / 3, k = F_IN + (tid - n * 3);
        xs[n * XPAD + k] = (_Float16)0.f;
    }
    __syncthreads();
    int w = tid >> 6, lane = tid & 63;
    int l16 = lane & 15, g = lane >> 4;
    const f16x8* ax  = (const f16x8*)&xs[(w * 16 + l16) * XPAD + g * 8];
    const f16x8* bw0 = (const f16x8*)&Wt[l16 * XPAD + g * 8];
    const f16x8* bw1 = (const f16x8*)&Wt[(16 + l16) * XPAD + g * 8];
    f16x8 a0 = ax[0],  a1 = ax[4];        // k = 8g.. / k = 32+8g..
    f16x8 b00 = bw0[0], b01 = bw0[4];
    f16x8 b10 = bw1[0], b11 = bw1[4];
    f32x4 acc0 = {0.f, 0.f, 0.f, 0.f};
    f32x4 acc1 = {0.f, 0.f, 0.f, 0.f};
    acc0 = __builtin_amdgcn_mfma_f32_16x16x32_f16(a0, b00, acc0, 0, 0, 0);
    acc0 = __builtin_amdgcn_mfma_f32_16x16x32_f16(a1, b01, acc0, 0, 0, 0);
    acc1 = __builtin_amdgcn_mfma_f32_16x16x32_f16(a0, b10, acc1, 0, 0, 0);
    acc1 = __builtin_amdgcn_mfma_f32_16x16x32_f16(a1, b11, acc1, 0, 0, 0);
    int nodebase = nb + w * 16 + g * 4;
    #pragma unroll
    for (int r = 0; r < 4; r++) {
        int node = nodebase + r;
        if (node < N) {
            float di = dinv[node];
            h[(long long)node * H + l16]      = __float2half(acc0[r] * di);
            h[(long long)node * H + 16 + l16] = __float2half(acc1[r] * di);
        }
    }
}

// ---------- fused agg + GEMM (r0 gather pattern + nontemporal streams) ----------
// Lane map per node (32 lanes): p = lane>>4 (edge parity), fp = lane&15
// (feature pair). 8 independent gathers in flight; accumulate with packed
// fp16 adds. Invalid slots gather the ZERO ROW at byte offset N*64.
// src_sorted reads and hout writes are NONTEMPORAL: they are single-use
// streams (9.6+9.4 MB/dispatch) that would otherwise evict the 9.6 MB
// gather table from L2 (theory for FETCH=105.7 of 153.6 MB).
__global__ __launch_bounds__(256) void agg_gemm_kernel(const int* __restrict__ row_start,
                                                       const int* __restrict__ src_sorted,
                                                       const float* __restrict__ dinv,
                                                       const __half* __restrict__ hs,
                                                       const float* __restrict__ b,
                                                       const float* __restrict__ Wn,
                                                       __half* __restrict__ hout, int N) {
    __shared__ float Ws[H * H];
    __shared__ float t[8 * H];
    int tid = threadIdx.x;
    for (int i = tid; i < H * H; i += 256) Ws[i] = Wn[i];
    int nl = tid >> 5;
    int lane32 = tid & 31;
    int p = lane32 >> 4;
    int fp = lane32 & 15;
    int node = blockIdx.x * 8 + nl;
    int zoff = N << 6;
    __half2 accA = __floats2half2_rn(0.f, 0.f);
    __half2 accB = __floats2half2_rn(0.f, 0.f);
    if (node < N) {
        const char* hbase = (const char*)hs + (fp << 2);
        int e0 = row_start[node], e1 = row_start[node + 1];
        int idxv = zoff;
        if (e0 + lane32 < e1) idxv = __builtin_nontemporal_load(src_sorted + e0 + lane32);
        for (int base = e0; base < e1; base += 32) {
            int w = e1 - base; if (w > 32) w = 32;
            int idxN = zoff;
            if (base + 32 + lane32 < e1) idxN = __builtin_nontemporal_load(src_sorted + base + 32 + lane32);
            for (int j = 0; j < w; j += 16) {
                int offs[8];
                #pragma unroll
                for (int k = 0; k < 8; k++) offs[k] = __shfl(idxv, j + 2 * k + p, 32);
                unsigned g[8];
                #pragma unroll
                for (int k = 0; k < 8; k++) g[k] = *(const unsigned*)(hbase + offs[k]);
                #pragma unroll
                for (int k = 0; k < 8; k += 2) {
                    accA = __hadd2(accA, *(__half2*)&g[k]);
                    accB = __hadd2(accB, *(__half2*)&g[k + 1]);
                }
            }
            idxv = idxN;
        }
    }
    __half2 accH = __hadd2(accA, accB);
    float2 acc = __half22float2(accH);
    acc.x += __shfl_xor(acc.x, 16, 32);
    acc.y += __shfl_xor(acc.y, 16, 32);
    if (node < N && p == 0) {
        float di = dinv[node];
        unsigned sv = *(const unsigned*)((const char*)hs + ((long long)node << 6) + (fp << 2));
        float2 s2 = __half22float2(*(__half2*)&sv);
        float2 bv = ((const float2*)b)[fp];
        float rx = fmaxf(di * (acc.x + s2.x) + bv.x, 0.f);
        float ry = fmaxf(di * (acc.y + s2.y) + bv.y, 0.f);
        ((float2*)&t[nl * H])[fp] = make_float2(rx, ry);
    }
    __syncthreads();
    if (node < N) {
        int f = lane32;
        float s = 0.f;
        #pragma unroll
        for (int k = 0; k < H; k++) s += t[nl * H + k] * Ws[k * H + f];
        __half hv = __float2half(s * dinv[node]);
        __builtin_nontemporal_store(__half_as_ushort(hv),
                                    (unsigned short*)&hout[(long long)node * H + f]);
    }
}

// ---------- final layer: X5 = relu(...), pool into 64 spread copies ----------
__global__ __launch_bounds__(256) void agg_pool_kernel(const int* __restrict__ row_start,
                                                       const int* __restrict__ src_sorted,
                                                       const float* __restrict__ dinv,
                                                       const __half* __restrict__ hs,
                                                       const float* __restrict__ b,
                                                       float* __restrict__ gs, int N) {
    __shared__ float t[8 * H];
    int tid = threadIdx.x;
    int nl = tid >> 5;
    int lane32 = tid & 31;
    int p = lane32 >> 4;
    int fp = lane32 & 15;
    int node = blockIdx.x * 8 + nl;
    int zoff = N << 6;
    __half2 accA = __floats2half2_rn(0.f, 0.f);
    __half2 accB = __floats2half2_rn(0.f, 0.f);
    if (node < N) {
        const char* hbase = (const char*)hs + (fp << 2);
        int e0 = row_start[node], e1 = row_start[node + 1];
        int idxv = zoff;
        if (e0 + lane32 < e1) idxv = __builtin_nontemporal_load(src_sorted + e0 + lane32);
        for (int base = e0; base < e1; base += 32) {
            int w = e1 - base; if (w > 32) w = 32;
            int idxN = zoff;
            if (base + 32 + lane32 < e1) idxN = __builtin_nontemporal_load(src_sorted + base + 32 + lane32);
            for (int j = 0; j < w; j += 16) {
                int offs[8];
                #pragma unroll
                for (int k = 0; k < 8; k++) offs[k] = __shfl(idxv, j + 2 * k + p, 32);
                unsigned g[8];
                #pragma unroll
                for (int k = 0; k < 8; k++) g[k] = *(const unsigned*)(hbase + offs[k]);
                #pragma unroll
                for (int k = 0; k < 8; k += 2) {
                    accA = __hadd2(accA, *(__half2*)&g[k]);
                    accB = __hadd2(accB, *(__half2*)&g[k + 1]);
                }
            }
            idxv = idxN;
        }
    }
    __half2 accH = __hadd2(accA, accB);
    float2 acc = __half22float2(accH);
    acc.x += __shfl_xor(acc.x, 16, 32);
    acc.y += __shfl_xor(acc.y, 16, 32);
    if (p == 0) {
        float2 r = make_float2(0.f, 0.f);
        if (node < N) {
            float di = dinv[node];
            unsigned sv = *(const unsigned*)((const char*)hs + ((long long)node << 6) + (fp << 2));
            float2 s2 = __half22float2(*(__half2*)&sv);
            float2 bv = ((const float2*)b)[fp];
            r.x = fmaxf(di * (acc.x + s2.x) + bv.x, 0.f);
            r.y = fmaxf(di * (acc.y + s2.y) + bv.y, 0.f);
        }
        ((float2*)&t[nl * H])[fp] = r;
    }
    __syncthreads();
    if (tid < H) {
        float s = 0.f;
        #pragma unroll
        for (int rI = 0; rI < 8; rI++) s += t[rI * H + tid];
        atomicAdd(&gs[(blockIdx.x & 63) * H + tid], s);
    }
}

// ---------- head ----------
__global__ __launch_bounds__(64) void head_kernel(const float* __restrict__ gs,
                                                  const float* __restrict__ Wl1,
                                                  const float* __restrict__ bl1,
                                                  const float* __restrict__ Wl2,
                                                  const float* __restrict__ bl2,
                                                  float* __restrict__ out) {
    __shared__ float gg[H];
    __shared__ float t[16];
    int tid = threadIdx.x;
    if (tid < H) {
        float s = 0.f;
        for (int c = 0; c < 64; c++) s += gs[c * H + tid];
        gg[tid] = s;
    }
    __syncthreads();
    if (tid < 16) {
        float s = bl1[tid];
        #pragma unroll
        for (int k = 0; k < 32; k++) s += gg[k] * Wl1[k * 16 + tid];
        t[tid] = fmaxf(s, 0.f);
    }
    __syncthreads();
    if (tid < 3) {
        float s = bl2[tid];
        #pragma unroll
        for (int k = 0; k < 16; k++) s += t[k] * Wl2[k * 3 + tid];
        out[tid] = s;
    }
}

extern "C" void kernel_launch(void* const* d_in, const int* in_sizes, int n_in,
                              void* d_out, int out_size, void* d_ws, size_t ws_size,
                              hipStream_t stream) {
    const float* x   = (const float*)d_in[0];
    const int*   ei  = (const int*)d_in[1];
    const float* W1  = (const float*)d_in[2];
    const float* b1  = (const float*)d_in[3];
    const float* W2  = (const float*)d_in[4];
    const float* b2  = (const float*)d_in[5];
    const float* W3  = (const float*)d_in[6];
    const float* b3  = (const float*)d_in[7];
    const float* W4  = (const float*)d_in[8];
    const float* b4  = (const float*)d_in[9];
    const float* Wl1 = (const float*)d_in[10];
    const float* bl1 = (const float*)d_in[11];
    const float* Wl2 = (const float*)d_in[12];
    const float* bl2 = (const float*)d_in[13];
    float* out = (float*)d_out;

    const int N = in_sizes[0] / F_IN;
    const int E = in_sizes[1] / 2;
    const int nbuck = (N + BUCK_SZ - 1) >> BUCK_BITS;      // 586 for N=150000
    const int B = (E + CHUNK - 1) / CHUNK;                 // 293 for E=2.4M
    const int nC = nbuck * B;

    char* ws = (char*)d_ws;
    size_t off = 0;
    auto alloc = [&](size_t bytes) {
        char* p = ws + off;
        off += (bytes + 255) & ~(size_t)255;
        return p;
    };
    float* dinv       = (float*)alloc((size_t)N * 4);
    int*   row_start  = (int*)alloc((size_t)(N + 1) * 4);
    int*   counts     = (int*)alloc((size_t)nC * 4);
    int*   countsS    = (int*)alloc((size_t)nC * 4);
    int*   btot2      = (int*)alloc(((size_t)nC / 256 + 2) * 4);
    int*   src_sorted = (int*)alloc((size_t)E * 4);
    int*   tmp        = (int*)alloc((size_t)E * 4);
    __half* bufA      = (__half*)alloc((size_t)(N + 1) * H * 2);   // fp16 rows + zero row
    __half* bufB      = (__half*)alloc((size_t)(N + 1) * H * 2);
    float* gs         = (float*)alloc(64 * H * 4);

    const int TB = 256;
    const int gC  = (nC + TB - 1) / TB;   // 675 blocks <= 1024 for scan2
    const int gN8 = (N + 7) / 8;
    const int gN64 = (N + 63) / 64;

    // ---- CSR build (no global atomics, no memsets — all folded) ----
    histA_kernel<<<B, TB, 0, stream>>>(ei, counts, gs, E, B, nbuck);
    scan1_kernel<<<gC, TB, 0, stream>>>(counts, countsS, btot2, nC);
    scan2_kernel<<<1, 1024, 0, stream>>>(btot2, gC);
    binB_kernel<<<B, TB, 0, stream>>>(ei, countsS, btot2, tmp, E, B, nbuck);
    binC_kernel<<<nbuck, TB, 0, stream>>>(countsS, btot2, tmp, src_sorted, row_start,
                                          dinv, bufA, bufB, N, E, B, nbuck);

    // ---- layers ----
    gemm1_kernel<<<gN64, TB, 0, stream>>>(x, W1, dinv, bufA, N);                                 // hs1
    agg_gemm_kernel<<<gN8, TB, 0, stream>>>(row_start, src_sorted, dinv, bufA, b1, W2, bufB, N); // hs2
    agg_gemm_kernel<<<gN8, TB, 0, stream>>>(row_start, src_sorted, dinv, bufB, b2, W3, bufA, N); // hs3
    agg_gemm_kernel<<<gN8, TB, 0, stream>>>(row_start, src_sorted, dinv, bufA, b3, W4, bufB, N); // hs4
    agg_pool_kernel<<<gN8, TB, 0, stream>>>(row_start, src_sorted, dinv, bufB, b4, gs, N);       // pool(X5)

    head_kernel<<<1, 64, 0, stream>>>(gs, Wl1, bl1, Wl2, bl2, out);
}

// Round 7
// 355.797 us; speedup vs baseline: 1.0216x; 1.0216x over previous
//
#include <hip/hip_runtime.h>
#include <hip/hip_fp16.h>

#define F_IN 61
#define H 32
#define BUCK_BITS 8                  // 256 nodes per bucket
#define BUCK_SZ   256
#define CHUNK     8192               // edges per block in hist/bin passes
#define XPAD 72                      // fp16 row pad: 144B rows -> 16B aligned b128 reads
#define CMAX 6144                    // binC LDS-staged bucket capacity (mean 4096, 32 sigma)

typedef _Float16 f16x8 __attribute__((ext_vector_type(8)));
typedef float    f32x4 __attribute__((ext_vector_type(4)));

// ---------- scan level 1: per-256-block exclusive scan + block totals ----------
__global__ __launch_bounds__(256) void scan1_kernel(const int* __restrict__ in,
                                                    int* __restrict__ scanned,
                                                    int* __restrict__ btot, int n) {
    __shared__ int s[256];
    int tid = threadIdx.x;
    int i = blockIdx.x * 256 + tid;
    int v = (i < n) ? in[i] : 0;
    s[tid] = v;
    __syncthreads();
    for (int off = 1; off < 256; off <<= 1) {
        int t = (tid >= off) ? s[tid - off] : 0;
        __syncthreads();
        s[tid] += t;
        __syncthreads();
    }
    if (i < n) scanned[i] = s[tid] - v;
    if (tid == 255) btot[blockIdx.x] = s[255];
}

// ---------- scan level 2: exclusive scan of block totals (single block) ----------
__global__ __launch_bounds__(1024) void scan2_kernel(int* __restrict__ btot, int nB) {
    __shared__ int s[1024];
    int tid = threadIdx.x;
    int v = (tid < nB) ? btot[tid] : 0;
    s[tid] = v;
    __syncthreads();
    for (int off = 1; off < 1024; off <<= 1) {
        int t = (tid >= off) ? s[tid - off] : 0;
        __syncthreads();
        s[tid] += t;
        __syncthreads();
    }
    if (tid < nB) btot[tid] = s[tid] - v;
}

// ---------- pass A: per-(block,bucket) histogram; block 0 also zeroes gs ----------
__global__ __launch_bounds__(256) void histA_kernel(const int* __restrict__ ei,
                                                    int* __restrict__ counts,
                                                    float* __restrict__ gs,
                                                    int E, int B, int nbuck) {
    __shared__ int h[640];
    int tid = threadIdx.x;
    if (blockIdx.x == 0) {
        #pragma unroll
        for (int r = 0; r < 8; r++) gs[r * 256 + tid] = 0.f;   // 64*H floats
    }
    for (int i = tid; i < nbuck; i += 256) h[i] = 0;
    __syncthreads();
    int e0 = blockIdx.x * CHUNK;
    int e1 = e0 + CHUNK; if (e1 > E) e1 = E;
    for (int e = e0 + tid; e < e1; e += 256)
        atomicAdd(&h[ei[E + e] >> BUCK_BITS], 1);
    __syncthreads();
    for (int i = tid; i < nbuck; i += 256) counts[i * B + blockIdx.x] = h[i];
}

// ---------- pass B: bin edges into per-(block,bucket) EXCLUSIVE ranges ----------
// Reads scan results directly (scan3 folded): excl[i] = countsS[i] + btot[i>>8].
// pack = (src<<8)|(dst&255); src < 2^18 fits.
__global__ __launch_bounds__(256) void binB_kernel(const int* __restrict__ ei,
                                                   const int* __restrict__ countsS,
                                                   const int* __restrict__ btot,
                                                   int* __restrict__ tmp,
                                                   int E, int B, int nbuck) {
    __shared__ int lcur[640];
    int tid = threadIdx.x;
    for (int i = tid; i < nbuck; i += 256) {
        int ci = i * B + blockIdx.x;
        lcur[i] = countsS[ci] + btot[ci >> 8];
    }
    __syncthreads();
    int e0 = blockIdx.x * CHUNK;
    int e1 = e0 + CHUNK; if (e1 > E) e1 = E;
    for (int e = e0 + tid; e < e1; e += 256) {
        int s = ei[e];
        int d = ei[E + e];
        int pos = atomicAdd(&lcur[d >> BUCK_BITS], 1);
        tmp[pos] = (s << BUCK_BITS) | (d & (BUCK_SZ - 1));
    }
}

// ---------- pass C: per-bucket degree + row_start + dinv + final CSR scatter ----------
// SINGLE global pass over tmp: the bucket slice (<= CMAX entries, uniform-branch
// fallback otherwise) is staged in LDS during the hist pass; the scatter then
// runs from LDS into an LDS obuf (local positions) and the final src_sorted
// write is a contiguous fully-coalesced copy. Measured ~-16us vs 2-pass (r6).
// src_sorted stores BYTE offsets (src*64) for the fp16 row table.
// Block 0 also writes the zero rows (index N) of both fp16 buffers.
__global__ __launch_bounds__(256) void binC_kernel(const int* __restrict__ countsS,
                                                   const int* __restrict__ btot,
                                                   const int* __restrict__ tmp,
                                                   int* __restrict__ src_sorted,
                                                   int* __restrict__ row_start,
                                                   float* __restrict__ dinv,
                                                   __half* __restrict__ bufA,
                                                   __half* __restrict__ bufB,
                                                   int N, int E, int B, int nbuck) {
    __shared__ int hist[BUCK_SZ];
    __shared__ int pre[BUCK_SZ];
    __shared__ int lcur[BUCK_SZ];
    __shared__ int ebuf[CMAX];
    __shared__ int obuf[CMAX];
    int tid = threadIdx.x;
    int b = blockIdx.x;
    int base = b << BUCK_BITS;
    if (b == 0 && tid < H) {                 // zero rows for padded gathers
        bufA[(size_t)N * H + tid] = __float2half(0.f);
        bufB[(size_t)N * H + tid] = __float2half(0.f);
    }
    int c0 = b * B;
    int e0 = countsS[c0] + btot[c0 >> 8];
    int e1 = E;
    if (b + 1 < nbuck) {
        int c1 = (b + 1) * B;
        e1 = countsS[c1] + btot[c1 >> 8];
    }
    int cnt = e1 - e0;
    bool fits = (cnt <= CMAX);               // block-uniform
    hist[tid] = 0;
    __syncthreads();
    if (fits) {
        for (int j = tid; j < cnt; j += 256) {
            int p = tmp[e0 + j];
            ebuf[j] = p;
            atomicAdd(&hist[p & (BUCK_SZ - 1)], 1);
        }
    } else {
        for (int j = tid; j < cnt; j += 256)
            atomicAdd(&hist[tmp[e0 + j] & (BUCK_SZ - 1)], 1);
    }
    __syncthreads();
    int v = hist[tid];
    pre[tid] = v;
    __syncthreads();
    for (int off = 1; off < 256; off <<= 1) {
        int t = (tid >= off) ? pre[tid - off] : 0;
        __syncthreads();
        pre[tid] += t;
        __syncthreads();
    }
    int excl = pre[tid] - v;
    int node = base + tid;
    if (node < N) {
        row_start[node] = e0 + excl;
        dinv[node] = rsqrtf((float)v + 1.0f);     // +1 self-loop
        if (node == N - 1) row_start[N] = E;
    }
    lcur[tid] = fits ? excl : (e0 + excl);
    __syncthreads();
    if (fits) {
        for (int j = tid; j < cnt; j += 256) {
            int p = ebuf[j];
            int pos = atomicAdd(&lcur[p & (BUCK_SZ - 1)], 1);
            obuf[pos] = (p >> BUCK_BITS) << 6;    // byte offset of fp16 row
        }
        __syncthreads();
        for (int j = tid; j < cnt; j += 256)      // coalesced stream-out
            src_sorted[e0 + j] = obuf[j];
    } else {
        for (int j = tid; j < cnt; j += 256) {
            int p = tmp[e0 + j];
            int pos = atomicAdd(&lcur[p & (BUCK_SZ - 1)], 1);
            src_sorted[pos] = (p >> BUCK_BITS) << 6;
        }
    }
}

// ---------- layer 1 dense via MFMA: hs1 = fp16( dinv * (x @ W1) ) ----------
// 64 nodes/block, 4 waves, each wave one 16-node M-tile. x and W^T staged as
// fp16 in LDS with 72-element row pad (144B rows: 16B-aligned ds_read_b128,
// even bank spread). K padded 61->64 with zeros. Per wave: 4 MFMAs
// (2 f-tiles x 2 K-steps), fp32 accumulate, dinv scale in epilogue.
__global__ __launch_bounds__(256) void gemm1_kernel(const float* __restrict__ x,
                                                    const float* __restrict__ W,
                                                    const float* __restrict__ dinv,
                                                    __half* __restrict__ h, int N) {
    __shared__ _Float16 Wt[H * XPAD];      // Wt[f][k] = W[k*32+f], k<61 else 0
    __shared__ _Float16 xs[64 * XPAD];     // xs[n][k], k<61 else 0
    int tid = threadIdx.x;
    for (int i = tid; i < 2048; i += 256) {          // k = 0..63, f = 0..31
        int k = i >> 5, f = i & 31;
        Wt[f * XPAD + k] = (k < F_IN) ? (_Float16)W[k * H + f] : (_Float16)0.f;
    }
    int nb = blockIdx.x * 64;
    int navail = N - nb; if (navail > 64) navail = 64;
    int lim = navail * F_IN;
    const float* xb = x + (long long)nb * F_IN;
    for (int i = tid; i < 64 * F_IN; i += 256) {     // coalesced dword stream
        int n = i / F_IN, k = i - n * F_IN;
        xs[n * XPAD + k] = (i < lim) ? (_Float16)xb[i] : (_Float16)0.f;
    }
    if (tid < 192) {                                  // zero pad k = 61..63
        int n = tid / 3, k = F_IN + (tid - n * 3);
        xs[n * XPAD + k] = (_Float16)0.f;
    }
    __syncthreads();
    int w = tid >> 6, lane = tid & 63;
    int l16 = lane & 15, g = lane >> 4;
    const f16x8* ax  = (const f16x8*)&xs[(w * 16 + l16) * XPAD + g * 8];
    const f16x8* bw0 = (const f16x8*)&Wt[l16 * XPAD + g * 8];
    const f16x8* bw1 = (const f16x8*)&Wt[(16 + l16) * XPAD + g * 8];
    f16x8 a0 = ax[0],  a1 = ax[4];        // k = 8g.. / k = 32+8g..
    f16x8 b00 = bw0[0], b01 = bw0[4];
    f16x8 b10 = bw1[0], b11 = bw1[4];
    f32x4 acc0 = {0.f, 0.f, 0.f, 0.f};
    f32x4 acc1 = {0.f, 0.f, 0.f, 0.f};
    acc0 = __builtin_amdgcn_mfma_f32_16x16x32_f16(a0, b00, acc0, 0, 0, 0);
    acc0 = __builtin_amdgcn_mfma_f32_16x16x32_f16(a1, b01, acc0, 0, 0, 0);
    acc1 = __builtin_amdgcn_mfma_f32_16x16x32_f16(a0, b10, acc1, 0, 0, 0);
    acc1 = __builtin_amdgcn_mfma_f32_16x16x32_f16(a1, b11, acc1, 0, 0, 0);
    int nodebase = nb + w * 16 + g * 4;
    #pragma unroll
    for (int r = 0; r < 4; r++) {
        int node = nodebase + r;
        if (node < N) {
            float di = dinv[node];
            h[(long long)node * H + l16]      = __float2half(acc0[r] * di);
            h[(long long)node * H + 16 + l16] = __float2half(acc1[r] * di);
        }
    }
}

// ---------- fused agg + GEMM (round-0 version: dword gathers, 2 rounds/chunk) --
// Lane map per node (32 lanes): p = lane>>4 (edge parity), fp = lane&15
// (feature pair). 8 independent gathers in flight; accumulate with packed
// fp16 adds (1 instr / 2 features) into two interleaved accumulators.
// Invalid slots gather the ZERO ROW at byte offset N*64.
// NOTE: plain (cached) loads/stores on purpose — r6 measured nontemporal
// hints at -10% (hout is the next layer's gather table; nt store evicts it).
__global__ __launch_bounds__(256) void agg_gemm_kernel(const int* __restrict__ row_start,
                                                       const int* __restrict__ src_sorted,
                                                       const float* __restrict__ dinv,
                                                       const __half* __restrict__ hs,
                                                       const float* __restrict__ b,
                                                       const float* __restrict__ Wn,
                                                       __half* __restrict__ hout, int N) {
    __shared__ float Ws[H * H];
    __shared__ float t[8 * H];
    int tid = threadIdx.x;
    for (int i = tid; i < H * H; i += 256) Ws[i] = Wn[i];
    int nl = tid >> 5;
    int lane32 = tid & 31;
    int p = lane32 >> 4;
    int fp = lane32 & 15;
    int node = blockIdx.x * 8 + nl;
    int zoff = N << 6;
    __half2 accA = __floats2half2_rn(0.f, 0.f);
    __half2 accB = __floats2half2_rn(0.f, 0.f);
    if (node < N) {
        const char* hbase = (const char*)hs + (fp << 2);
        int e0 = row_start[node], e1 = row_start[node + 1];
        int idxv = (e0 + lane32 < e1) ? src_sorted[e0 + lane32] : zoff;
        for (int base = e0; base < e1; base += 32) {
            int w = e1 - base; if (w > 32) w = 32;
            int idxN = (base + 32 + lane32 < e1) ? src_sorted[base + 32 + lane32] : zoff;
            for (int j = 0; j < w; j += 16) {
                int offs[8];
                #pragma unroll
                for (int k = 0; k < 8; k++) offs[k] = __shfl(idxv, j + 2 * k + p, 32);
                unsigned g[8];
                #pragma unroll
                for (int k = 0; k < 8; k++) g[k] = *(const unsigned*)(hbase + offs[k]);
                #pragma unroll
                for (int k = 0; k < 8; k += 2) {
                    accA = __hadd2(accA, *(__half2*)&g[k]);
                    accB = __hadd2(accB, *(__half2*)&g[k + 1]);
                }
            }
            idxv = idxN;
        }
    }
    __half2 accH = __hadd2(accA, accB);
    float2 acc = __half22float2(accH);
    acc.x += __shfl_xor(acc.x, 16, 32);
    acc.y += __shfl_xor(acc.y, 16, 32);
    if (node < N && p == 0) {
        float di = dinv[node];
        unsigned sv = *(const unsigned*)((const char*)hs + ((long long)node << 6) + (fp << 2));
        float2 s2 = __half22float2(*(__half2*)&sv);
        float2 bv = ((const float2*)b)[fp];
        float rx = fmaxf(di * (acc.x + s2.x) + bv.x, 0.f);
        float ry = fmaxf(di * (acc.y + s2.y) + bv.y, 0.f);
        ((float2*)&t[nl * H])[fp] = make_float2(rx, ry);
    }
    __syncthreads();
    if (node < N) {
        int f = lane32;
        float s = 0.f;
        #pragma unroll
        for (int k = 0; k < H; k++) s += t[nl * H + k] * Ws[k * H + f];
        hout[(long long)node * H + f] = __float2half(s * dinv[node]);
    }
}

// ---------- final layer: X5 = relu(...), pool into 64 spread copies ----------
__global__ __launch_bounds__(256) void agg_pool_kernel(const int* __restrict__ row_start,
                                                       const int* __restrict__ src_sorted,
                                                       const float* __restrict__ dinv,
                                                       const __half* __restrict__ hs,
                                                       const float* __restrict__ b,
                                                       float* __restrict__ gs, int N) {
    __shared__ float t[8 * H];
    int tid = threadIdx.x;
    int nl = tid >> 5;
    int lane32 = tid & 31;
    int p = lane32 >> 4;
    int fp = lane32 & 15;
    int node = blockIdx.x * 8 + nl;
    int zoff = N << 6;
    __half2 accA = __floats2half2_rn(0.f, 0.f);
    __half2 accB = __floats2half2_rn(0.f, 0.f);
    if (node < N) {
        const char* hbase = (const char*)hs + (fp << 2);
        int e0 = row_start[node], e1 = row_start[node + 1];
        int idxv = (e0 + lane32 < e1) ? src_sorted[e0 + lane32] : zoff;
        for (int base = e0; base < e1; base += 32) {
            int w = e1 - base; if (w > 32) w = 32;
            int idxN = (base + 32 + lane32 < e1) ? src_sorted[base + 32 + lane32] : zoff;
            for (int j = 0; j < w; j += 16) {
                int offs[8];
                #pragma unroll
                for (int k = 0; k < 8; k++) offs[k] = __shfl(idxv, j + 2 * k + p, 32);
                unsigned g[8];
                #pragma unroll
                for (int k = 0; k < 8; k++) g[k] = *(const unsigned*)(hbase + offs[k]);
                #pragma unroll
                for (int k = 0; k < 8; k += 2) {
                    accA = __hadd2(accA, *(__half2*)&g[k]);
                    accB = __hadd2(accB, *(__half2*)&g[k + 1]);
                }
            }
            idxv = idxN;
        }
    }
    __half2 accH = __hadd2(accA, accB);
    float2 acc = __half22float2(accH);
    acc.x += __shfl_xor(acc.x, 16, 32);
    acc.y += __shfl_xor(acc.y, 16, 32);
    if (p == 0) {
        float2 r = make_float2(0.f, 0.f);
        if (node < N) {
            float di = dinv[node];
            unsigned sv = *(const unsigned*)((const char*)hs + ((long long)node << 6) + (fp << 2));
            float2 s2 = __half22float2(*(__half2*)&sv);
            float2 bv = ((const float2*)b)[fp];
            r.x = fmaxf(di * (acc.x + s2.x) + bv.x, 0.f);
            r.y = fmaxf(di * (acc.y + s2.y) + bv.y, 0.f);
        }
        ((float2*)&t[nl * H])[fp] = r;
    }
    __syncthreads();
    if (tid < H) {
        float s = 0.f;
        #pragma unroll
        for (int rI = 0; rI < 8; rI++) s += t[rI * H + tid];
        atomicAdd(&gs[(blockIdx.x & 63) * H + tid], s);
    }
}

// ---------- head ----------
__global__ __launch_bounds__(64) void head_kernel(const float* __restrict__ gs,
                                                  const float* __restrict__ Wl1,
                                                  const float* __restrict__ bl1,
                                                  const float* __restrict__ Wl2,
                                                  const float* __restrict__ bl2,
                                                  float* __restrict__ out) {
    __shared__ float gg[H];
    __shared__ float t[16];
    int tid = threadIdx.x;
    if (tid < H) {
        float s = 0.f;
        for (int c = 0; c < 64; c++) s += gs[c * H + tid];
        gg[tid] = s;
    }
    __syncthreads();
    if (tid < 16) {
        float s = bl1[tid];
        #pragma unroll
        for (int k = 0; k < 32; k++) s += gg[k] * Wl1[k * 16 + tid];
        t[tid] = fmaxf(s, 0.f);
    }
    __syncthreads();
    if (tid < 3) {
        float s = bl2[tid];
        #pragma unroll
        for (int k = 0; k < 16; k++) s += t[k] * Wl2[k * 3 + tid];
        out[tid] = s;
    }
}

extern "C" void kernel_launch(void* const* d_in, const int* in_sizes, int n_in,
                              void* d_out, int out_size, void* d_ws, size_t ws_size,
                              hipStream_t stream) {
    const float* x   = (const float*)d_in[0];
    const int*   ei  = (const int*)d_in[1];
    const float* W1  = (const float*)d_in[2];
    const float* b1  = (const float*)d_in[3];
    const float* W2  = (const float*)d_in[4];
    const float* b2  = (const float*)d_in[5];
    const float* W3  = (const float*)d_in[6];
    const float* b3  = (const float*)d_in[7];
    const float* W4  = (const float*)d_in[8];
    const float* b4  = (const float*)d_in[9];
    const float* Wl1 = (const float*)d_in[10];
    const float* bl1 = (const float*)d_in[11];
    const float* Wl2 = (const float*)d_in[12];
    const float* bl2 = (const float*)d_in[13];
    float* out = (float*)d_out;

    const int N = in_sizes[0] / F_IN;
    const int E = in_sizes[1] / 2;
    const int nbuck = (N + BUCK_SZ - 1) >> BUCK_BITS;      // 586 for N=150000
    const int B = (E + CHUNK - 1) / CHUNK;                 // 293 for E=2.4M
    const int nC = nbuck * B;

    char* ws = (char*)d_ws;
    size_t off = 0;
    auto alloc = [&](size_t bytes) {
        char* p = ws + off;
        off += (bytes + 255) & ~(size_t)255;
        return p;
    };
    float* dinv       = (float*)alloc((size_t)N * 4);
    int*   row_start  = (int*)alloc((size_t)(N + 1) * 4);
    int*   counts     = (int*)alloc((size_t)nC * 4);
    int*   countsS    = (int*)alloc((size_t)nC * 4);
    int*   btot2      = (int*)alloc(((size_t)nC / 256 + 2) * 4);
    int*   src_sorted = (int*)alloc((size_t)E * 4);
    int*   tmp        = (int*)alloc((size_t)E * 4);
    __half* bufA      = (__half*)alloc((size_t)(N + 1) * H * 2);   // fp16 rows + zero row
    __half* bufB      = (__half*)alloc((size_t)(N + 1) * H * 2);
    float* gs         = (float*)alloc(64 * H * 4);

    const int TB = 256;
    const int gC  = (nC + TB - 1) / TB;   // 675 blocks <= 1024 for scan2
    const int gN8 = (N + 7) / 8;
    const int gN64 = (N + 63) / 64;

    // ---- CSR build (no global atomics, no memsets — all folded) ----
    histA_kernel<<<B, TB, 0, stream>>>(ei, counts, gs, E, B, nbuck);
    scan1_kernel<<<gC, TB, 0, stream>>>(counts, countsS, btot2, nC);
    scan2_kernel<<<1, 1024, 0, stream>>>(btot2, gC);
    binB_kernel<<<B, TB, 0, stream>>>(ei, countsS, btot2, tmp, E, B, nbuck);
    binC_kernel<<<nbuck, TB, 0, stream>>>(countsS, btot2, tmp, src_sorted, row_start,
                                          dinv, bufA, bufB, N, E, B, nbuck);

    // ---- layers ----
    gemm1_kernel<<<gN64, TB, 0, stream>>>(x, W1, dinv, bufA, N);                                 // hs1
    agg_gemm_kernel<<<gN8, TB, 0, stream>>>(row_start, src_sorted, dinv, bufA, b1, W2, bufB, N); // hs2
    agg_gemm_kernel<<<gN8, TB, 0, stream>>>(row_start, src_sorted, dinv, bufB, b2, W3, bufA, N); // hs3
    agg_gemm_kernel<<<gN8, TB, 0, stream>>>(row_start, src_sorted, dinv, bufA, b3, W4, bufB, N); // hs4
    agg_pool_kernel<<<gN8, TB, 0, stream>>>(row_start, src_sorted, dinv, bufB, b4, gs, N);       // pool(X5)

    head_kernel<<<1, 64, 0, stream>>>(gs, Wl1, bl1, Wl2, bl2, out);
}

// Round 8
// 353.464 us; speedup vs baseline: 1.0284x; 1.0066x over previous
//
#include <hip/hip_runtime.h>
#include <hip/hip_fp16.h>

#define F_IN 61
#define H 32
#define BUCK_BITS 8                  // 256 nodes per bucket
#define BUCK_SZ   256
#define CHUNK     8192               // edges per block in hist/bin passes
#define XPAD 72                      // fp16 row pad: 144B rows -> 16B aligned b128 reads
#define CMAX 6144                    // binC LDS-staged bucket capacity (mean 4096, 32 sigma)

typedef _Float16 f16x8 __attribute__((ext_vector_type(8)));
typedef float    f32x4 __attribute__((ext_vector_type(4)));

// ---------- scan level 1: per-256-block exclusive scan + block totals ----------
__global__ __launch_bounds__(256) void scan1_kernel(const int* __restrict__ in,
                                                    int* __restrict__ scanned,
                                                    int* __restrict__ btot, int n) {
    __shared__ int s[256];
    int tid = threadIdx.x;
    int i = blockIdx.x * 256 + tid;
    int v = (i < n) ? in[i] : 0;
    s[tid] = v;
    __syncthreads();
    for (int off = 1; off < 256; off <<= 1) {
        int t = (tid >= off) ? s[tid - off] : 0;
        __syncthreads();
        s[tid] += t;
        __syncthreads();
    }
    if (i < n) scanned[i] = s[tid] - v;
    if (tid == 255) btot[blockIdx.x] = s[255];
}

// ---------- scan level 2: exclusive scan of block totals (single block) ----------
__global__ __launch_bounds__(1024) void scan2_kernel(int* __restrict__ btot, int nB) {
    __shared__ int s[1024];
    int tid = threadIdx.x;
    int v = (tid < nB) ? btot[tid] : 0;
    s[tid] = v;
    __syncthreads();
    for (int off = 1; off < 1024; off <<= 1) {
        int t = (tid >= off) ? s[tid - off] : 0;
        __syncthreads();
        s[tid] += t;
        __syncthreads();
    }
    if (tid < nB) btot[tid] = s[tid] - v;
}

// ---------- pass A: per-(block,bucket) histogram; block 0 also zeroes gs ----------
__global__ __launch_bounds__(256) void histA_kernel(const int* __restrict__ ei,
                                                    int* __restrict__ counts,
                                                    float* __restrict__ gs,
                                                    int E, int B, int nbuck) {
    __shared__ int h[640];
    int tid = threadIdx.x;
    if (blockIdx.x == 0) {
        #pragma unroll
        for (int r = 0; r < 8; r++) gs[r * 256 + tid] = 0.f;   // 64*H floats
    }
    for (int i = tid; i < nbuck; i += 256) h[i] = 0;
    __syncthreads();
    int e0 = blockIdx.x * CHUNK;
    int e1 = e0 + CHUNK; if (e1 > E) e1 = E;
    for (int e = e0 + tid; e < e1; e += 256)
        atomicAdd(&h[ei[E + e] >> BUCK_BITS], 1);
    __syncthreads();
    for (int i = tid; i < nbuck; i += 256) counts[i * B + blockIdx.x] = h[i];
}

// ---------- pass B: bin edges into per-(block,bucket) EXCLUSIVE ranges ----------
// LDS counting-sort per chunk (binC's trick applied to binB): local histogram
// -> segmented LDS scan -> local scatter into ebuf (bucket-sorted) -> write-out
// as CONTIGUOUS runs per (block,bucket) via gshift[b] = gbase[b] - lbase[b].
// Replaces the random 4B atomic-positioned global scatter; the second edge
// read hits L2 (32KB chunk slice). pack = (src<<8)|(dst&255).
__global__ __launch_bounds__(256) void binB_kernel(const int* __restrict__ ei,
                                                   const int* __restrict__ countsS,
                                                   const int* __restrict__ btot,
                                                   int* __restrict__ tmp,
                                                   int E, int B, int nbuck) {
    __shared__ int gshift[640];            // gbase[b] - local exclusive base[b]
    __shared__ int lhist[640];
    __shared__ int lcur[640];              // running local cursor (starts at lbase)
    __shared__ int ebuf[CHUNK];
    __shared__ unsigned short bbuf[CHUNK]; // bucket id per staged slot
    __shared__ int sc[256];
    int tid = threadIdx.x;
    for (int i = tid; i < 640; i += 256) lhist[i] = 0;
    int e0 = blockIdx.x * CHUNK;
    int e1 = e0 + CHUNK; if (e1 > E) e1 = E;
    int cnt = e1 - e0;
    __syncthreads();
    // pass 1: local histogram over dst buckets
    for (int e = e0 + tid; e < e1; e += 256)
        atomicAdd(&lhist[ei[E + e] >> BUCK_BITS], 1);
    __syncthreads();
    // segmented exclusive scan of lhist[640] with 256 threads + carry
    int carry = 0;
    for (int s0 = 0; s0 < 640; s0 += 256) {
        int idx = s0 + tid;
        int v = (idx < 640) ? lhist[idx] : 0;
        sc[tid] = v;
        __syncthreads();
        for (int off = 1; off < 256; off <<= 1) {
            int t = (tid >= off) ? sc[tid - off] : 0;
            __syncthreads();
            sc[tid] += t;
            __syncthreads();
        }
        int excl = sc[tid] - v + carry;
        if (idx < 640) {
            lcur[idx] = excl;
            if (idx < nbuck) {
                int ci = idx * B + blockIdx.x;
                gshift[idx] = (countsS[ci] + btot[ci >> 8]) - excl;
            }
        }
        carry += sc[255];
        __syncthreads();
    }
    // pass 2: local scatter (edge re-read is L2-hot)
    for (int e = e0 + tid; e < e1; e += 256) {
        int s = ei[e];
        int d = ei[E + e];
        int b = d >> BUCK_BITS;
        int lp = atomicAdd(&lcur[b], 1);
        ebuf[lp] = (s << BUCK_BITS) | (d & (BUCK_SZ - 1));
        bbuf[lp] = (unsigned short)b;
    }
    __syncthreads();
    // write-out: consecutive j within a bucket run -> consecutive global addrs
    for (int j = tid; j < cnt; j += 256)
        tmp[j + gshift[bbuf[j]]] = ebuf[j];
}

// ---------- pass C: per-bucket degree + row_start + dinv + final CSR scatter ----------
// SINGLE global pass over tmp: the bucket slice (<= CMAX entries, uniform-branch
// fallback otherwise) is staged in LDS during the hist pass; the scatter then
// runs from LDS into an LDS obuf (local positions) and the final src_sorted
// write is a contiguous fully-coalesced copy. Measured ~-16us vs 2-pass (r6).
// src_sorted stores BYTE offsets (src*64) for the fp16 row table.
// Block 0 also writes the zero rows (index N) of both fp16 buffers.
__global__ __launch_bounds__(256) void binC_kernel(const int* __restrict__ countsS,
                                                   const int* __restrict__ btot,
                                                   const int* __restrict__ tmp,
                                                   int* __restrict__ src_sorted,
                                                   int* __restrict__ row_start,
                                                   float* __restrict__ dinv,
                                                   __half* __restrict__ bufA,
                                                   __half* __restrict__ bufB,
                                                   int N, int E, int B, int nbuck) {
    __shared__ int hist[BUCK_SZ];
    __shared__ int pre[BUCK_SZ];
    __shared__ int lcur[BUCK_SZ];
    __shared__ int ebuf[CMAX];
    __shared__ int obuf[CMAX];
    int tid = threadIdx.x;
    int b = blockIdx.x;
    int base = b << BUCK_BITS;
    if (b == 0 && tid < H) {                 // zero rows for padded gathers
        bufA[(size_t)N * H + tid] = __float2half(0.f);
        bufB[(size_t)N * H + tid] = __float2half(0.f);
    }
    int c0 = b * B;
    int e0 = countsS[c0] + btot[c0 >> 8];
    int e1 = E;
    if (b + 1 < nbuck) {
        int c1 = (b + 1) * B;
        e1 = countsS[c1] + btot[c1 >> 8];
    }
    int cnt = e1 - e0;
    bool fits = (cnt <= CMAX);               // block-uniform
    hist[tid] = 0;
    __syncthreads();
    if (fits) {
        for (int j = tid; j < cnt; j += 256) {
            int p = tmp[e0 + j];
            ebuf[j] = p;
            atomicAdd(&hist[p & (BUCK_SZ - 1)], 1);
        }
    } else {
        for (int j = tid; j < cnt; j += 256)
            atomicAdd(&hist[tmp[e0 + j] & (BUCK_SZ - 1)], 1);
    }
    __syncthreads();
    int v = hist[tid];
    pre[tid] = v;
    __syncthreads();
    for (int off = 1; off < 256; off <<= 1) {
        int t = (tid >= off) ? pre[tid - off] : 0;
        __syncthreads();
        pre[tid] += t;
        __syncthreads();
    }
    int excl = pre[tid] - v;
    int node = base + tid;
    if (node < N) {
        row_start[node] = e0 + excl;
        dinv[node] = rsqrtf((float)v + 1.0f);     // +1 self-loop
        if (node == N - 1) row_start[N] = E;
    }
    lcur[tid] = fits ? excl : (e0 + excl);
    __syncthreads();
    if (fits) {
        for (int j = tid; j < cnt; j += 256) {
            int p = ebuf[j];
            int pos = atomicAdd(&lcur[p & (BUCK_SZ - 1)], 1);
            obuf[pos] = (p >> BUCK_BITS) << 6;    // byte offset of fp16 row
        }
        __syncthreads();
        for (int j = tid; j < cnt; j += 256)      // coalesced stream-out
            src_sorted[e0 + j] = obuf[j];
    } else {
        for (int j = tid; j < cnt; j += 256) {
            int p = tmp[e0 + j];
            int pos = atomicAdd(&lcur[p & (BUCK_SZ - 1)], 1);
            src_sorted[pos] = (p >> BUCK_BITS) << 6;
        }
    }
}

// ---------- layer 1 dense via MFMA: hs1 = fp16( dinv * (x @ W1) ) ----------
// 64 nodes/block, 4 waves, each wave one 16-node M-tile. x and W^T staged as
// fp16 in LDS with 72-element row pad (144B rows: 16B-aligned ds_read_b128,
// even bank spread). K padded 61->64 with zeros. Per wave: 4 MFMAs
// (2 f-tiles x 2 K-steps), fp32 accumulate, dinv scale in epilogue.
__global__ __launch_bounds__(256) void gemm1_kernel(const float* __restrict__ x,
                                                    const float* __restrict__ W,
                                                    const float* __restrict__ dinv,
                                                    __half* __restrict__ h, int N) {
    __shared__ _Float16 Wt[H * XPAD];      // Wt[f][k] = W[k*32+f], k<61 else 0
    __shared__ _Float16 xs[64 * XPAD];     // xs[n][k], k<61 else 0
    int tid = threadIdx.x;
    for (int i = tid; i < 2048; i += 256) {          // k = 0..63, f = 0..31
        int k = i >> 5, f = i & 31;
        Wt[f * XPAD + k] = (k < F_IN) ? (_Float16)W[k * H + f] : (_Float16)0.f;
    }
    int nb = blockIdx.x * 64;
    int navail = N - nb; if (navail > 64) navail = 64;
    int lim = navail * F_IN;
    const float* xb = x + (long long)nb * F_IN;
    for (int i = tid; i < 64 * F_IN; i += 256) {     // coalesced dword stream
        int n = i / F_IN, k = i - n * F_IN;
        xs[n * XPAD + k] = (i < lim) ? (_Float16)xb[i] : (_Float16)0.f;
    }
    if (tid < 192) {                                  // zero pad k = 61..63
        int n = tid / 3, k = F_IN + (tid - n * 3);
        xs[n * XPAD + k] = (_Float16)0.f;
    }
    __syncthreads();
    int w = tid >> 6, lane = tid & 63;
    int l16 = lane & 15, g = lane >> 4;
    const f16x8* ax  = (const f16x8*)&xs[(w * 16 + l16) * XPAD + g * 8];
    const f16x8* bw0 = (const f16x8*)&Wt[l16 * XPAD + g * 8];
    const f16x8* bw1 = (const f16x8*)&Wt[(16 + l16) * XPAD + g * 8];
    f16x8 a0 = ax[0],  a1 = ax[4];        // k = 8g.. / k = 32+8g..
    f16x8 b00 = bw0[0], b01 = bw0[4];
    f16x8 b10 = bw1[0], b11 = bw1[4];
    f32x4 acc0 = {0.f, 0.f, 0.f, 0.f};
    f32x4 acc1 = {0.f, 0.f, 0.f, 0.f};
    acc0 = __builtin_amdgcn_mfma_f32_16x16x32_f16(a0, b00, acc0, 0, 0, 0);
    acc0 = __builtin_amdgcn_mfma_f32_16x16x32_f16(a1, b01, acc0, 0, 0, 0);
    acc1 = __builtin_amdgcn_mfma_f32_16x16x32_f16(a0, b10, acc1, 0, 0, 0);
    acc1 = __builtin_amdgcn_mfma_f32_16x16x32_f16(a1, b11, acc1, 0, 0, 0);
    int nodebase = nb + w * 16 + g * 4;
    #pragma unroll
    for (int r = 0; r < 4; r++) {
        int node = nodebase + r;
        if (node < N) {
            float di = dinv[node];
            h[(long long)node * H + l16]      = __float2half(acc0[r] * di);
            h[(long long)node * H + 16 + l16] = __float2half(acc1[r] * di);
        }
    }
}

// ---------- fused agg + GEMM (round-0 version: dword gathers, 2 rounds/chunk) --
// Lane map per node (32 lanes): p = lane>>4 (edge parity), fp = lane&15
// (feature pair). 8 independent gathers in flight; accumulate with packed
// fp16 adds (1 instr / 2 features) into two interleaved accumulators.
// Invalid slots gather the ZERO ROW at byte offset N*64.
// NOTE: plain (cached) loads/stores on purpose — r6 measured nontemporal
// hints at -10% (hout is the next layer's gather table; nt store evicts it).
__global__ __launch_bounds__(256) void agg_gemm_kernel(const int* __restrict__ row_start,
                                                       const int* __restrict__ src_sorted,
                                                       const float* __restrict__ dinv,
                                                       const __half* __restrict__ hs,
                                                       const float* __restrict__ b,
                                                       const float* __restrict__ Wn,
                                                       __half* __restrict__ hout, int N) {
    __shared__ float Ws[H * H];
    __shared__ float t[8 * H];
    int tid = threadIdx.x;
    for (int i = tid; i < H * H; i += 256) Ws[i] = Wn[i];
    int nl = tid >> 5;
    int lane32 = tid & 31;
    int p = lane32 >> 4;
    int fp = lane32 & 15;
    int node = blockIdx.x * 8 + nl;
    int zoff = N << 6;
    __half2 accA = __floats2half2_rn(0.f, 0.f);
    __half2 accB = __floats2half2_rn(0.f, 0.f);
    if (node < N) {
        const char* hbase = (const char*)hs + (fp << 2);
        int e0 = row_start[node], e1 = row_start[node + 1];
        int idxv = (e0 + lane32 < e1) ? src_sorted[e0 + lane32] : zoff;
        for (int base = e0; base < e1; base += 32) {
            int w = e1 - base; if (w > 32) w = 32;
            int idxN = (base + 32 + lane32 < e1) ? src_sorted[base + 32 + lane32] : zoff;
            for (int j = 0; j < w; j += 16) {
                int offs[8];
                #pragma unroll
                for (int k = 0; k < 8; k++) offs[k] = __shfl(idxv, j + 2 * k + p, 32);
                unsigned g[8];
                #pragma unroll
                for (int k = 0; k < 8; k++) g[k] = *(const unsigned*)(hbase + offs[k]);
                #pragma unroll
                for (int k = 0; k < 8; k += 2) {
                    accA = __hadd2(accA, *(__half2*)&g[k]);
                    accB = __hadd2(accB, *(__half2*)&g[k + 1]);
                }
            }
            idxv = idxN;
        }
    }
    __half2 accH = __hadd2(accA, accB);
    float2 acc = __half22float2(accH);
    acc.x += __shfl_xor(acc.x, 16, 32);
    acc.y += __shfl_xor(acc.y, 16, 32);
    if (node < N && p == 0) {
        float di = dinv[node];
        unsigned sv = *(const unsigned*)((const char*)hs + ((long long)node << 6) + (fp << 2));
        float2 s2 = __half22float2(*(__half2*)&sv);
        float2 bv = ((const float2*)b)[fp];
        float rx = fmaxf(di * (acc.x + s2.x) + bv.x, 0.f);
        float ry = fmaxf(di * (acc.y + s2.y) + bv.y, 0.f);
        ((float2*)&t[nl * H])[fp] = make_float2(rx, ry);
    }
    __syncthreads();
    if (node < N) {
        int f = lane32;
        float s = 0.f;
        #pragma unroll
        for (int k = 0; k < H; k++) s += t[nl * H + k] * Ws[k * H + f];
        hout[(long long)node * H + f] = __float2half(s * dinv[node]);
    }
}

// ---------- final layer: X5 = relu(...), pool into 64 spread copies ----------
__global__ __launch_bounds__(256) void agg_pool_kernel(const int* __restrict__ row_start,
                                                       const int* __restrict__ src_sorted,
                                                       const float* __restrict__ dinv,
                                                       const __half* __restrict__ hs,
                                                       const float* __restrict__ b,
                                                       float* __restrict__ gs, int N) {
    __shared__ float t[8 * H];
    int tid = threadIdx.x;
    int nl = tid >> 5;
    int lane32 = tid & 31;
    int p = lane32 >> 4;
    int fp = lane32 & 15;
    int node = blockIdx.x * 8 + nl;
    int zoff = N << 6;
    __half2 accA = __floats2half2_rn(0.f, 0.f);
    __half2 accB = __floats2half2_rn(0.f, 0.f);
    if (node < N) {
        const char* hbase = (const char*)hs + (fp << 2);
        int e0 = row_start[node], e1 = row_start[node + 1];
        int idxv = (e0 + lane32 < e1) ? src_sorted[e0 + lane32] : zoff;
        for (int base = e0; base < e1; base += 32) {
            int w = e1 - base; if (w > 32) w = 32;
            int idxN = (base + 32 + lane32 < e1) ? src_sorted[base + 32 + lane32] : zoff;
            for (int j = 0; j < w; j += 16) {
                int offs[8];
                #pragma unroll
                for (int k = 0; k < 8; k++) offs[k] = __shfl(idxv, j + 2 * k + p, 32);
                unsigned g[8];
                #pragma unroll
                for (int k = 0; k < 8; k++) g[k] = *(const unsigned*)(hbase + offs[k]);
                #pragma unroll
                for (int k = 0; k < 8; k += 2) {
                    accA = __hadd2(accA, *(__half2*)&g[k]);
                    accB = __hadd2(accB, *(__half2*)&g[k + 1]);
                }
            }
            idxv = idxN;
        }
    }
    __half2 accH = __hadd2(accA, accB);
    float2 acc = __half22float2(accH);
    acc.x += __shfl_xor(acc.x, 16, 32);
    acc.y += __shfl_xor(acc.y, 16, 32);
    if (p == 0) {
        float2 r = make_float2(0.f, 0.f);
        if (node < N) {
            float di = dinv[node];
            unsigned sv = *(const unsigned*)((const char*)hs + ((long long)node << 6) + (fp << 2));
            float2 s2 = __half22float2(*(__half2*)&sv);
            float2 bv = ((const float2*)b)[fp];
            r.x = fmaxf(di * (acc.x + s2.x) + bv.x, 0.f);
            r.y = fmaxf(di * (acc.y + s2.y) + bv.y, 0.f);
        }
        ((float2*)&t[nl * H])[fp] = r;
    }
    __syncthreads();
    if (tid < H) {
        float s = 0.f;
        #pragma unroll
        for (int rI = 0; rI < 8; rI++) s += t[rI * H + tid];
        atomicAdd(&gs[(blockIdx.x & 63) * H + tid], s);
    }
}

// ---------- head ----------
__global__ __launch_bounds__(64) void head_kernel(const float* __restrict__ gs,
                                                  const float* __restrict__ Wl1,
                                                  const float* __restrict__ bl1,
                                                  const float* __restrict__ Wl2,
                                                  const float* __restrict__ bl2,
                                                  float* __restrict__ out) {
    __shared__ float gg[H];
    __shared__ float t[16];
    int tid = threadIdx.x;
    if (tid < H) {
        float s = 0.f;
        for (int c = 0; c < 64; c++) s += gs[c * H + tid];
        gg[tid] = s;
    }
    __syncthreads();
    if (tid < 16) {
        float s = bl1[tid];
        #pragma unroll
        for (int k = 0; k < 32; k++) s += gg[k] * Wl1[k * 16 + tid];
        t[tid] = fmaxf(s, 0.f);
    }
    __syncthreads();
    if (tid < 3) {
        float s = bl2[tid];
        #pragma unroll
        for (int k = 0; k < 16; k++) s += t[k] * Wl2[k * 3 + tid];
        out[tid] = s;
    }
}

extern "C" void kernel_launch(void* const* d_in, const int* in_sizes, int n_in,
                              void* d_out, int out_size, void* d_ws, size_t ws_size,
                              hipStream_t stream) {
    const float* x   = (const float*)d_in[0];
    const int*   ei  = (const int*)d_in[1];
    const float* W1  = (const float*)d_in[2];
    const float* b1  = (const float*)d_in[3];
    const float* W2  = (const float*)d_in[4];
    const float* b2  = (const float*)d_in[5];
    const float* W3  = (const float*)d_in[6];
    const float* b3  = (const float*)d_in[7];
    const float* W4  = (const float*)d_in[8];
    const float* b4  = (const float*)d_in[9];
    const float* Wl1 = (const float*)d_in[10];
    const float* bl1 = (const float*)d_in[11];
    const float* Wl2 = (const float*)d_in[12];
    const float* bl2 = (const float*)d_in[13];
    float* out = (float*)d_out;

    const int N = in_sizes[0] / F_IN;
    const int E = in_sizes[1] / 2;
    const int nbuck = (N + BUCK_SZ - 1) >> BUCK_BITS;      // 586 for N=150000
    const int B = (E + CHUNK - 1) / CHUNK;                 // 293 for E=2.4M
    const int nC = nbuck * B;

    char* ws = (char*)d_ws;
    size_t off = 0;
    auto alloc = [&](size_t bytes) {
        char* p = ws + off;
        off += (bytes + 255) & ~(size_t)255;
        return p;
    };
    float* dinv       = (float*)alloc((size_t)N * 4);
    int*   row_start  = (int*)alloc((size_t)(N + 1) * 4);
    int*   counts     = (int*)alloc((size_t)nC * 4);
    int*   countsS    = (int*)alloc((size_t)nC * 4);
    int*   btot2      = (int*)alloc(((size_t)nC / 256 + 2) * 4);
    int*   src_sorted = (int*)alloc((size_t)E * 4);
    int*   tmp        = (int*)alloc((size_t)E * 4);
    __half* bufA      = (__half*)alloc((size_t)(N + 1) * H * 2);   // fp16 rows + zero row
    __half* bufB      = (__half*)alloc((size_t)(N + 1) * H * 2);
    float* gs         = (float*)alloc(64 * H * 4);

    const int TB = 256;
    const int gC  = (nC + TB - 1) / TB;   // 675 blocks <= 1024 for scan2
    const int gN8 = (N + 7) / 8;
    const int gN64 = (N + 63) / 64;

    // ---- CSR build (no global atomics, no memsets — all folded) ----
    histA_kernel<<<B, TB, 0, stream>>>(ei, counts, gs, E, B, nbuck);
    scan1_kernel<<<gC, TB, 0, stream>>>(counts, countsS, btot2, nC);
    scan2_kernel<<<1, 1024, 0, stream>>>(btot2, gC);
    binB_kernel<<<B, TB, 0, stream>>>(ei, countsS, btot2, tmp, E, B, nbuck);
    binC_kernel<<<nbuck, TB, 0, stream>>>(countsS, btot2, tmp, src_sorted, row_start,
                                          dinv, bufA, bufB, N, E, B, nbuck);

    // ---- layers ----
    gemm1_kernel<<<gN64, TB, 0, stream>>>(x, W1, dinv, bufA, N);                                 // hs1
    agg_gemm_kernel<<<gN8, TB, 0, stream>>>(row_start, src_sorted, dinv, bufA, b1, W2, bufB, N); // hs2
    agg_gemm_kernel<<<gN8, TB, 0, stream>>>(row_start, src_sorted, dinv, bufB, b2, W3, bufA, N); // hs3
    agg_gemm_kernel<<<gN8, TB, 0, stream>>>(row_start, src_sorted, dinv, bufA, b3, W4, bufB, N); // hs4
    agg_pool_kernel<<<gN8, TB, 0, stream>>>(row_start, src_sorted, dinv, bufB, b4, gs, N);       // pool(X5)

    head_kernel<<<1, 64, 0, stream>>>(gs, Wl1, bl1, Wl2, bl2, out);
}

// Round 9
// 352.554 us; speedup vs baseline: 1.0310x; 1.0026x over previous
//
#include <hip/hip_runtime.h>
#include <hip/hip_fp16.h>

#define F_IN 61
#define H 32
#define BUCK_BITS 8                  // 256 nodes per bucket
#define BUCK_SZ   256
#define CHUNK     2048               // edges per block in hist/bin passes (small: grid occupancy)
#define XPAD 72                      // fp16 row pad: 144B rows -> 16B aligned b128 reads
#define CMAX 6144                    // binC LDS-staged bucket capacity (mean 4096, 32 sigma)

typedef _Float16 f16x8 __attribute__((ext_vector_type(8)));
typedef float    f32x4 __attribute__((ext_vector_type(4)));

// ---------- scan level 1: per-256-block exclusive scan + block totals ----------
__global__ __launch_bounds__(256) void scan1_kernel(const int* __restrict__ in,
                                                    int* __restrict__ scanned,
                                                    int* __restrict__ btot, int n) {
    __shared__ int s[256];
    int tid = threadIdx.x;
    int i = blockIdx.x * 256 + tid;
    int v = (i < n) ? in[i] : 0;
    s[tid] = v;
    __syncthreads();
    for (int off = 1; off < 256; off <<= 1) {
        int t = (tid >= off) ? s[tid - off] : 0;
        __syncthreads();
        s[tid] += t;
        __syncthreads();
    }
    if (i < n) scanned[i] = s[tid] - v;
    if (tid == 255) btot[blockIdx.x] = s[255];
}

// ---------- scan level 2: exclusive scan of block totals (single block) ----------
// 4 elements/thread (capacity 4096): thread-local prefix + 1024-thread block
// scan of per-thread sums. Needed since CHUNK=2048 -> gC ~ 2683 > 1024.
__global__ __launch_bounds__(1024) void scan2_kernel(int* __restrict__ btot, int nB) {
    __shared__ int s[1024];
    int tid = threadIdx.x;
    int base = tid << 2;
    int v0 = (base + 0 < nB) ? btot[base + 0] : 0;
    int v1 = (base + 1 < nB) ? btot[base + 1] : 0;
    int v2 = (base + 2 < nB) ? btot[base + 2] : 0;
    int v3 = (base + 3 < nB) ? btot[base + 3] : 0;
    int sum = v0 + v1 + v2 + v3;
    s[tid] = sum;
    __syncthreads();
    for (int off = 1; off < 1024; off <<= 1) {
        int t = (tid >= off) ? s[tid - off] : 0;
        __syncthreads();
        s[tid] += t;
        __syncthreads();
    }
    int run = s[tid] - sum;                 // exclusive base for this thread's 4
    if (base + 0 < nB) { btot[base + 0] = run; run += v0; }
    if (base + 1 < nB) { btot[base + 1] = run; run += v1; }
    if (base + 2 < nB) { btot[base + 2] = run; run += v2; }
    if (base + 3 < nB) { btot[base + 3] = run; }
}

// ---------- pass A: per-(block,bucket) histogram; block 0 also zeroes gs ----------
__global__ __launch_bounds__(256) void histA_kernel(const int* __restrict__ ei,
                                                    int* __restrict__ counts,
                                                    float* __restrict__ gs,
                                                    int E, int B, int nbuck) {
    __shared__ int h[640];
    int tid = threadIdx.x;
    if (blockIdx.x == 0) {
        #pragma unroll
        for (int r = 0; r < 8; r++) gs[r * 256 + tid] = 0.f;   // 64*H floats
    }
    for (int i = tid; i < nbuck; i += 256) h[i] = 0;
    __syncthreads();
    int e0 = blockIdx.x * CHUNK;
    int e1 = e0 + CHUNK; if (e1 > E) e1 = E;
    for (int e = e0 + tid; e < e1; e += 256)
        atomicAdd(&h[ei[E + e] >> BUCK_BITS], 1);
    __syncthreads();
    for (int i = tid; i < nbuck; i += 256) counts[i * B + blockIdx.x] = h[i];
}

// ---------- pass B: bin edges into per-(block,bucket) EXCLUSIVE ranges ----------
// LDS counting-sort per chunk: local histogram -> segmented LDS scan -> local
// scatter into ebuf (bucket-sorted) -> run write-out via gshift[b].
// CHUNK=2048 keeps LDS ~21KB -> 7 blocks/CU; grid 1172 blocks ~ 4.6/CU.
// pack = (src<<8)|(dst&255); src < 2^18 fits.
__global__ __launch_bounds__(256) void binB_kernel(const int* __restrict__ ei,
                                                   const int* __restrict__ countsS,
                                                   const int* __restrict__ btot,
                                                   int* __restrict__ tmp,
                                                   int E, int B, int nbuck) {
    __shared__ int gshift[640];            // gbase[b] - local exclusive base[b]
    __shared__ int lhist[640];
    __shared__ int lcur[640];              // running local cursor (starts at lbase)
    __shared__ int ebuf[CHUNK];
    __shared__ unsigned short bbuf[CHUNK]; // bucket id per staged slot
    __shared__ int sc[256];
    int tid = threadIdx.x;
    for (int i = tid; i < 640; i += 256) lhist[i] = 0;
    int e0 = blockIdx.x * CHUNK;
    int e1 = e0 + CHUNK; if (e1 > E) e1 = E;
    int cnt = e1 - e0;
    __syncthreads();
    // pass 1: local histogram over dst buckets
    for (int e = e0 + tid; e < e1; e += 256)
        atomicAdd(&lhist[ei[E + e] >> BUCK_BITS], 1);
    __syncthreads();
    // segmented exclusive scan of lhist[640] with 256 threads + carry
    int carry = 0;
    for (int s0 = 0; s0 < 640; s0 += 256) {
        int idx = s0 + tid;
        int v = (idx < 640) ? lhist[idx] : 0;
        sc[tid] = v;
        __syncthreads();
        for (int off = 1; off < 256; off <<= 1) {
            int t = (tid >= off) ? sc[tid - off] : 0;
            __syncthreads();
            sc[tid] += t;
            __syncthreads();
        }
        int excl = sc[tid] - v + carry;
        if (idx < 640) {
            lcur[idx] = excl;
            if (idx < nbuck) {
                int ci = idx * B + blockIdx.x;
                gshift[idx] = (countsS[ci] + btot[ci >> 8]) - excl;
            }
        }
        carry += sc[255];
        __syncthreads();
    }
    // pass 2: local scatter (edge re-read is L2-hot)
    for (int e = e0 + tid; e < e1; e += 256) {
        int s = ei[e];
        int d = ei[E + e];
        int b = d >> BUCK_BITS;
        int lp = atomicAdd(&lcur[b], 1);
        ebuf[lp] = (s << BUCK_BITS) | (d & (BUCK_SZ - 1));
        bbuf[lp] = (unsigned short)b;
    }
    __syncthreads();
    // write-out: consecutive j within a bucket run -> consecutive global addrs
    for (int j = tid; j < cnt; j += 256)
        tmp[j + gshift[bbuf[j]]] = ebuf[j];
}

// ---------- pass C: per-bucket degree + row_start + dinv + final CSR scatter ----------
// SINGLE global pass over tmp: the bucket slice (<= CMAX entries, uniform-branch
// fallback otherwise) is staged in LDS during the hist pass; the scatter then
// runs from LDS into an LDS obuf (local positions) and the final src_sorted
// write is a contiguous fully-coalesced copy. Measured ~-16us vs 2-pass (r6).
// src_sorted stores BYTE offsets (src*64) for the fp16 row table.
// Block 0 also writes the zero rows (index N) of both fp16 buffers.
__global__ __launch_bounds__(256) void binC_kernel(const int* __restrict__ countsS,
                                                   const int* __restrict__ btot,
                                                   const int* __restrict__ tmp,
                                                   int* __restrict__ src_sorted,
                                                   int* __restrict__ row_start,
                                                   float* __restrict__ dinv,
                                                   __half* __restrict__ bufA,
                                                   __half* __restrict__ bufB,
                                                   int N, int E, int B, int nbuck) {
    __shared__ int hist[BUCK_SZ];
    __shared__ int pre[BUCK_SZ];
    __shared__ int lcur[BUCK_SZ];
    __shared__ int ebuf[CMAX];
    __shared__ int obuf[CMAX];
    int tid = threadIdx.x;
    int b = blockIdx.x;
    int base = b << BUCK_BITS;
    if (b == 0 && tid < H) {                 // zero rows for padded gathers
        bufA[(size_t)N * H + tid] = __float2half(0.f);
        bufB[(size_t)N * H + tid] = __float2half(0.f);
    }
    int c0 = b * B;
    int e0 = countsS[c0] + btot[c0 >> 8];
    int e1 = E;
    if (b + 1 < nbuck) {
        int c1 = (b + 1) * B;
        e1 = countsS[c1] + btot[c1 >> 8];
    }
    int cnt = e1 - e0;
    bool fits = (cnt <= CMAX);               // block-uniform
    hist[tid] = 0;
    __syncthreads();
    if (fits) {
        for (int j = tid; j < cnt; j += 256) {
            int p = tmp[e0 + j];
            ebuf[j] = p;
            atomicAdd(&hist[p & (BUCK_SZ - 1)], 1);
        }
    } else {
        for (int j = tid; j < cnt; j += 256)
            atomicAdd(&hist[tmp[e0 + j] & (BUCK_SZ - 1)], 1);
    }
    __syncthreads();
    int v = hist[tid];
    pre[tid] = v;
    __syncthreads();
    for (int off = 1; off < 256; off <<= 1) {
        int t = (tid >= off) ? pre[tid - off] : 0;
        __syncthreads();
        pre[tid] += t;
        __syncthreads();
    }
    int excl = pre[tid] - v;
    int node = base + tid;
    if (node < N) {
        row_start[node] = e0 + excl;
        dinv[node] = rsqrtf((float)v + 1.0f);     // +1 self-loop
        if (node == N - 1) row_start[N] = E;
    }
    lcur[tid] = fits ? excl : (e0 + excl);
    __syncthreads();
    if (fits) {
        for (int j = tid; j < cnt; j += 256) {
            int p = ebuf[j];
            int pos = atomicAdd(&lcur[p & (BUCK_SZ - 1)], 1);
            obuf[pos] = (p >> BUCK_BITS) << 6;    // byte offset of fp16 row
        }
        __syncthreads();
        for (int j = tid; j < cnt; j += 256)      // coalesced stream-out
            src_sorted[e0 + j] = obuf[j];
    } else {
        for (int j = tid; j < cnt; j += 256) {
            int p = tmp[e0 + j];
            int pos = atomicAdd(&lcur[p & (BUCK_SZ - 1)], 1);
            src_sorted[pos] = (p >> BUCK_BITS) << 6;
        }
    }
}

// ---------- layer 1 dense via MFMA: hs1 = fp16( dinv * (x @ W1) ) ----------
// 64 nodes/block, 4 waves, each wave one 16-node M-tile. x and W^T staged as
// fp16 in LDS with 72-element row pad (144B rows: 16B-aligned ds_read_b128,
// even bank spread). K padded 61->64 with zeros. Per wave: 4 MFMAs
// (2 f-tiles x 2 K-steps), fp32 accumulate, dinv scale in epilogue.
__global__ __launch_bounds__(256) void gemm1_kernel(const float* __restrict__ x,
                                                    const float* __restrict__ W,
                                                    const float* __restrict__ dinv,
                                                    __half* __restrict__ h, int N) {
    __shared__ _Float16 Wt[H * XPAD];      // Wt[f][k] = W[k*32+f], k<61 else 0
    __shared__ _Float16 xs[64 * XPAD];     // xs[n][k], k<61 else 0
    int tid = threadIdx.x;
    for (int i = tid; i < 2048; i += 256) {          // k = 0..63, f = 0..31
        int k = i >> 5, f = i & 31;
        Wt[f * XPAD + k] = (k < F_IN) ? (_Float16)W[k * H + f] : (_Float16)0.f;
    }
    int nb = blockIdx.x * 64;
    int navail = N - nb; if (navail > 64) navail = 64;
    int lim = navail * F_IN;
    const float* xb = x + (long long)nb * F_IN;
    for (int i = tid; i < 64 * F_IN; i += 256) {     // coalesced dword stream
        int n = i / F_IN, k = i - n * F_IN;
        xs[n * XPAD + k] = (i < lim) ? (_Float16)xb[i] : (_Float16)0.f;
    }
    if (tid < 192) {                                  // zero pad k = 61..63
        int n = tid / 3, k = F_IN + (tid - n * 3);
        xs[n * XPAD + k] = (_Float16)0.f;
    }
    __syncthreads();
    int w = tid >> 6, lane = tid & 63;
    int l16 = lane & 15, g = lane >> 4;
    const f16x8* ax  = (const f16x8*)&xs[(w * 16 + l16) * XPAD + g * 8];
    const f16x8* bw0 = (const f16x8*)&Wt[l16 * XPAD + g * 8];
    const f16x8* bw1 = (const f16x8*)&Wt[(16 + l16) * XPAD + g * 8];
    f16x8 a0 = ax[0],  a1 = ax[4];        // k = 8g.. / k = 32+8g..
    f16x8 b00 = bw0[0], b01 = bw0[4];
    f16x8 b10 = bw1[0], b11 = bw1[4];
    f32x4 acc0 = {0.f, 0.f, 0.f, 0.f};
    f32x4 acc1 = {0.f, 0.f, 0.f, 0.f};
    acc0 = __builtin_amdgcn_mfma_f32_16x16x32_f16(a0, b00, acc0, 0, 0, 0);
    acc0 = __builtin_amdgcn_mfma_f32_16x16x32_f16(a1, b01, acc0, 0, 0, 0);
    acc1 = __builtin_amdgcn_mfma_f32_16x16x32_f16(a0, b10, acc1, 0, 0, 0);
    acc1 = __builtin_amdgcn_mfma_f32_16x16x32_f16(a1, b11, acc1, 0, 0, 0);
    int nodebase = nb + w * 16 + g * 4;
    #pragma unroll
    for (int r = 0; r < 4; r++) {
        int node = nodebase + r;
        if (node < N) {
            float di = dinv[node];
            h[(long long)node * H + l16]      = __float2half(acc0[r] * di);
            h[(long long)node * H + 16 + l16] = __float2half(acc1[r] * di);
        }
    }
}

// ---------- fused agg + GEMM (round-0 version: dword gathers, 2 rounds/chunk) --
// Lane map per node (32 lanes): p = lane>>4 (edge parity), fp = lane&15
// (feature pair). 8 independent gathers in flight; accumulate with packed
// fp16 adds (1 instr / 2 features) into two interleaved accumulators.
// Invalid slots gather the ZERO ROW at byte offset N*64.
// NOTE: plain (cached) loads/stores on purpose — r6 measured nontemporal
// hints at -10% (hout is the next layer's gather table; nt store evicts it).
__global__ __launch_bounds__(256) void agg_gemm_kernel(const int* __restrict__ row_start,
                                                       const int* __restrict__ src_sorted,
                                                       const float* __restrict__ dinv,
                                                       const __half* __restrict__ hs,
                                                       const float* __restrict__ b,
                                                       const float* __restrict__ Wn,
                                                       __half* __restrict__ hout, int N) {
    __shared__ float Ws[H * H];
    __shared__ float t[8 * H];
    int tid = threadIdx.x;
    for (int i = tid; i < H * H; i += 256) Ws[i] = Wn[i];
    int nl = tid >> 5;
    int lane32 = tid & 31;
    int p = lane32 >> 4;
    int fp = lane32 & 15;
    int node = blockIdx.x * 8 + nl;
    int zoff = N << 6;
    __half2 accA = __floats2half2_rn(0.f, 0.f);
    __half2 accB = __floats2half2_rn(0.f, 0.f);
    if (node < N) {
        const char* hbase = (const char*)hs + (fp << 2);
        int e0 = row_start[node], e1 = row_start[node + 1];
        int idxv = (e0 + lane32 < e1) ? src_sorted[e0 + lane32] : zoff;
        for (int base = e0; base < e1; base += 32) {
            int w = e1 - base; if (w > 32) w = 32;
            int idxN = (base + 32 + lane32 < e1) ? src_sorted[base + 32 + lane32] : zoff;
            for (int j = 0; j < w; j += 16) {
                int offs[8];
                #pragma unroll
                for (int k = 0; k < 8; k++) offs[k] = __shfl(idxv, j + 2 * k + p, 32);
                unsigned g[8];
                #pragma unroll
                for (int k = 0; k < 8; k++) g[k] = *(const unsigned*)(hbase + offs[k]);
                #pragma unroll
                for (int k = 0; k < 8; k += 2) {
                    accA = __hadd2(accA, *(__half2*)&g[k]);
                    accB = __hadd2(accB, *(__half2*)&g[k + 1]);
                }
            }
            idxv = idxN;
        }
    }
    __half2 accH = __hadd2(accA, accB);
    float2 acc = __half22float2(accH);
    acc.x += __shfl_xor(acc.x, 16, 32);
    acc.y += __shfl_xor(acc.y, 16, 32);
    if (node < N && p == 0) {
        float di = dinv[node];
        unsigned sv = *(const unsigned*)((const char*)hs + ((long long)node << 6) + (fp << 2));
        float2 s2 = __half22float2(*(__half2*)&sv);
        float2 bv = ((const float2*)b)[fp];
        float rx = fmaxf(di * (acc.x + s2.x) + bv.x, 0.f);
        float ry = fmaxf(di * (acc.y + s2.y) + bv.y, 0.f);
        ((float2*)&t[nl * H])[fp] = make_float2(rx, ry);
    }
    __syncthreads();
    if (node < N) {
        int f = lane32;
        float s = 0.f;
        #pragma unroll
        for (int k = 0; k < H; k++) s += t[nl * H + k] * Ws[k * H + f];
        hout[(long long)node * H + f] = __float2half(s * dinv[node]);
    }
}

// ---------- final layer: X5 = relu(...), pool into 64 spread copies ----------
__global__ __launch_bounds__(256) void agg_pool_kernel(const int* __restrict__ row_start,
                                                       const int* __restrict__ src_sorted,
                                                       const float* __restrict__ dinv,
                                                       const __half* __restrict__ hs,
                                                       const float* __restrict__ b,
                                                       float* __restrict__ gs, int N) {
    __shared__ float t[8 * H];
    int tid = threadIdx.x;
    int nl = tid >> 5;
    int lane32 = tid & 31;
    int p = lane32 >> 4;
    int fp = lane32 & 15;
    int node = blockIdx.x * 8 + nl;
    int zoff = N << 6;
    __half2 accA = __floats2half2_rn(0.f, 0.f);
    __half2 accB = __floats2half2_rn(0.f, 0.f);
    if (node < N) {
        const char* hbase = (const char*)hs + (fp << 2);
        int e0 = row_start[node], e1 = row_start[node + 1];
        int idxv = (e0 + lane32 < e1) ? src_sorted[e0 + lane32] : zoff;
        for (int base = e0; base < e1; base += 32) {
            int w = e1 - base; if (w > 32) w = 32;
            int idxN = (base + 32 + lane32 < e1) ? src_sorted[base + 32 + lane32] : zoff;
            for (int j = 0; j < w; j += 16) {
                int offs[8];
                #pragma unroll
                for (int k = 0; k < 8; k++) offs[k] = __shfl(idxv, j + 2 * k + p, 32);
                unsigned g[8];
                #pragma unroll
                for (int k = 0; k < 8; k++) g[k] = *(const unsigned*)(hbase + offs[k]);
                #pragma unroll
                for (int k = 0; k < 8; k += 2) {
                    accA = __hadd2(accA, *(__half2*)&g[k]);
                    accB = __hadd2(accB, *(__half2*)&g[k + 1]);
                }
            }
            idxv = idxN;
        }
    }
    __half2 accH = __hadd2(accA, accB);
    float2 acc = __half22float2(accH);
    acc.x += __shfl_xor(acc.x, 16, 32);
    acc.y += __shfl_xor(acc.y, 16, 32);
    if (p == 0) {
        float2 r = make_float2(0.f, 0.f);
        if (node < N) {
            float di = dinv[node];
            unsigned sv = *(const unsigned*)((const char*)hs + ((long long)node << 6) + (fp << 2));
            float2 s2 = __half22float2(*(__half2*)&sv);
            float2 bv = ((const float2*)b)[fp];
            r.x = fmaxf(di * (acc.x + s2.x) + bv.x, 0.f);
            r.y = fmaxf(di * (acc.y + s2.y) + bv.y, 0.f);
        }
        ((float2*)&t[nl * H])[fp] = r;
    }
    __syncthreads();
    if (tid < H) {
        float s = 0.f;
        #pragma unroll
        for (int rI = 0; rI < 8; rI++) s += t[rI * H + tid];
        atomicAdd(&gs[(blockIdx.x & 63) * H + tid], s);
    }
}

// ---------- head ----------
__global__ __launch_bounds__(64) void head_kernel(const float* __restrict__ gs,
                                                  const float* __restrict__ Wl1,
                                                  const float* __restrict__ bl1,
                                                  const float* __restrict__ Wl2,
                                                  const float* __restrict__ bl2,
                                                  float* __restrict__ out) {
    __shared__ float gg[H];
    __shared__ float t[16];
    int tid = threadIdx.x;
    if (tid < H) {
        float s = 0.f;
        for (int c = 0; c < 64; c++) s += gs[c * H + tid];
        gg[tid] = s;
    }
    __syncthreads();
    if (tid < 16) {
        float s = bl1[tid];
        #pragma unroll
        for (int k = 0; k < 32; k++) s += gg[k] * Wl1[k * 16 + tid];
        t[tid] = fmaxf(s, 0.f);
    }
    __syncthreads();
    if (tid < 3) {
        float s = bl2[tid];
        #pragma unroll
        for (int k = 0; k < 16; k++) s += t[k] * Wl2[k * 3 + tid];
        out[tid] = s;
    }
}

extern "C" void kernel_launch(void* const* d_in, const int* in_sizes, int n_in,
                              void* d_out, int out_size, void* d_ws, size_t ws_size,
                              hipStream_t stream) {
    const float* x   = (const float*)d_in[0];
    const int*   ei  = (const int*)d_in[1];
    const float* W1  = (const float*)d_in[2];
    const float* b1  = (const float*)d_in[3];
    const float* W2  = (const float*)d_in[4];
    const float* b2  = (const float*)d_in[5];
    const float* W3  = (const float*)d_in[6];
    const float* b3  = (const float*)d_in[7];
    const float* W4  = (const float*)d_in[8];
    const float* b4  = (const float*)d_in[9];
    const float* Wl1 = (const float*)d_in[10];
    const float* bl1 = (const float*)d_in[11];
    const float* Wl2 = (const float*)d_in[12];
    const float* bl2 = (const float*)d_in[13];
    float* out = (float*)d_out;

    const int N = in_sizes[0] / F_IN;
    const int E = in_sizes[1] / 2;
    const int nbuck = (N + BUCK_SZ - 1) >> BUCK_BITS;      // 586 for N=150000
    const int B = (E + CHUNK - 1) / CHUNK;                 // 1172 for E=2.4M
    const int nC = nbuck * B;                              // ~687K

    char* ws = (char*)d_ws;
    size_t off = 0;
    auto alloc = [&](size_t bytes) {
        char* p = ws + off;
        off += (bytes + 255) & ~(size_t)255;
        return p;
    };
    float* dinv       = (float*)alloc((size_t)N * 4);
    int*   row_start  = (int*)alloc((size_t)(N + 1) * 4);
    int*   counts     = (int*)alloc((size_t)nC * 4);
    int*   countsS    = (int*)alloc((size_t)nC * 4);
    int*   btot2      = (int*)alloc(((size_t)nC / 256 + 2) * 4);
    int*   src_sorted = (int*)alloc((size_t)E * 4);
    int*   tmp        = (int*)alloc((size_t)E * 4);
    __half* bufA      = (__half*)alloc((size_t)(N + 1) * H * 2);   // fp16 rows + zero row
    __half* bufB      = (__half*)alloc((size_t)(N + 1) * H * 2);
    float* gs         = (float*)alloc(64 * H * 4);

    const int TB = 256;
    const int gC  = (nC + TB - 1) / TB;   // ~2683 blocks <= 4096 for scan2
    const int gN8 = (N + 7) / 8;
    const int gN64 = (N + 63) / 64;

    // ---- CSR build (no global atomics, no memsets — all folded) ----
    histA_kernel<<<B, TB, 0, stream>>>(ei, counts, gs, E, B, nbuck);
    scan1_kernel<<<gC, TB, 0, stream>>>(counts, countsS, btot2, nC);
    scan2_kernel<<<1, 1024, 0, stream>>>(btot2, gC);
    binB_kernel<<<B, TB, 0, stream>>>(ei, countsS, btot2, tmp, E, B, nbuck);
    binC_kernel<<<nbuck, TB, 0, stream>>>(countsS, btot2, tmp, src_sorted, row_start,
                                          dinv, bufA, bufB, N, E, B, nbuck);

    // ---- layers ----
    gemm1_kernel<<<gN64, TB, 0, stream>>>(x, W1, dinv, bufA, N);                                 // hs1
    agg_gemm_kernel<<<gN8, TB, 0, stream>>>(row_start, src_sorted, dinv, bufA, b1, W2, bufB, N); // hs2
    agg_gemm_kernel<<<gN8, TB, 0, stream>>>(row_start, src_sorted, dinv, bufB, b2, W3, bufA, N); // hs3
    agg_gemm_kernel<<<gN8, TB, 0, stream>>>(row_start, src_sorted, dinv, bufA, b3, W4, bufB, N); // hs4
    agg_pool_kernel<<<gN8, TB, 0, stream>>>(row_start, src_sorted, dinv, bufB, b4, gs, N);       // pool(X5)

    head_kernel<<<1, 64, 0, stream>>>(gs, Wl1, bl1, Wl2, bl2, out);
}